// Round 3
// baseline (249.101 us; speedup 1.0000x reference)
//
#include <hip/hip_runtime.h>
#include <hip/hip_bf16.h>

// Problem: B=64, S=2048, D=256, VOCAB=288
//   day = TE[...,0] % 7 ; tod = TE[...,1] % T
//   h   = relu(W1[day] + W1[7+tod] + b1)          [M,256] fp32, never materialized
//   out = h @ W2 + b2                             [M,256] -> FP32 (reference output dtype)
// M = 131072. GEMM via mfma_f32_16x16x32_bf16, fp32 accumulate.
// TE may arrive as int32 or int64 words -> runtime-detected flag in d_ws.

typedef __bf16 bf16x8 __attribute__((ext_vector_type(8)));
typedef float  f32x4  __attribute__((ext_vector_type(4)));

#define M_TOTAL   131072
#define BM        128          // rows per block (4 waves x 32 rows)

// ws layout: [0, 131072) bytes = W2T bf16 [256][256]; at byte 131072: int flag (1 = TE int64)

// ---- prep: W2 [d][e] fp32 -> W2T [e][d] bf16; + TE dtype probe ------------
__global__ __launch_bounds__(256) void prep_w2t(const float* __restrict__ W2,
                                                __bf16* __restrict__ W2T,
                                                const int* __restrict__ TE32,
                                                int* __restrict__ flag) {
    int idx = blockIdx.x * 256 + threadIdx.x;   // 65536 total
    int e = idx & 255;
    int d = idx >> 8;
    W2T[e * 256 + d] = (__bf16)W2[d * 256 + e];

    // TE dtype probe: under int64, odd int32 words are high words of values
    // < 288 -> all zero. Under int32 they are tod values (OR != 0 w.p. ~1).
    if (blockIdx.x == 0 && threadIdx.x < 64) {
        int v = 0;
        for (int i = (int)threadIdx.x; i < 2048; i += 64) v |= TE32[2 * i + 1];
        unsigned long long nz = __ballot(v != 0);
        if (threadIdx.x == 0) *flag = (nz == 0ull) ? 1 : 0;
    }
}

// ---- main ------------------------------------------------------------------
__global__ __launch_bounds__(256) void temb_gemm(
        const int*  __restrict__ TE32,  // [M,2] int32 or int64 word view
        const int*  __restrict__ Tp,    // scalar T (low word either way)
        const float* __restrict__ W1,   // [295,256]
        const float* __restrict__ b1,   // [256]
        const __bf16* __restrict__ W2T, // [256 e][256 d] bf16
        const float* __restrict__ b2,   // [256]
        const int*  __restrict__ flag,  // 1 if TE is int64
        float* __restrict__ out)        // [M,256] fp32
{
    const int T    = Tp[0];
    const int is64 = *flag;             // wave-uniform
    const int wave = threadIdx.x >> 6;
    const int lane = threadIdx.x & 63;
    const int m    = lane & 15;       // A row within tile / C col within tile
    const int quad = lane >> 4;       // k-chunk selector / C row-group
    const int rowBase = blockIdx.x * BM + wave * 32;

    // ---- build A fragments (h in bf16) for 2 m-tiles x 8 k-steps ----
    // A layout: A[m = lane&15][k = quad*8 + j]
    bf16x8 afrag[2][8];
#pragma unroll
    for (int t = 0; t < 2; ++t) {
        const int row = rowBase + t * 16 + m;
        int day, tod;
        if (is64) {
            const int4 te = *(const int4*)(TE32 + 4 * row);  // low words at .x/.z
            day = te.x; tod = te.z;
        } else {
            const int2 te = *(const int2*)(TE32 + 2 * row);
            day = te.x; tod = te.y;
        }
        day %= 7; tod %= T;
        const float* __restrict__ wa = W1 + day * 256;
        const float* __restrict__ wb = W1 + (7 + tod) * 256;
#pragma unroll
        for (int ks = 0; ks < 8; ++ks) {
            const int k0 = ks * 32 + quad * 8;
            f32x4 a0 = *(const f32x4*)(wa + k0);
            f32x4 a1 = *(const f32x4*)(wa + k0 + 4);
            f32x4 c0 = *(const f32x4*)(wb + k0);
            f32x4 c1 = *(const f32x4*)(wb + k0 + 4);
            f32x4 d0 = *(const f32x4*)(b1 + k0);
            f32x4 d1 = *(const f32x4*)(b1 + k0 + 4);
            bf16x8 f;
#pragma unroll
            for (int j = 0; j < 4; ++j) {
                float h0 = a0[j] + c0[j] + d0[j];
                float h1 = a1[j] + c1[j] + d1[j];
                f[j]     = (__bf16)fmaxf(h0, 0.0f);
                f[j + 4] = (__bf16)fmaxf(h1, 0.0f);
            }
            afrag[t][ks] = f;
        }
    }

    // ---- N loop: 16 col-tiles of 16; B frag reused across both m-tiles ----
    // B layout: B[k = quad*8 + j][n = lane&15]  == W2T[n][k...k+7] contiguous
#pragma unroll 4
    for (int nt = 0; nt < 16; ++nt) {
        const int ncol = nt * 16 + m;
        const __bf16* __restrict__ wp = W2T + ncol * 256 + quad * 8;
        f32x4 acc0 = {0.f, 0.f, 0.f, 0.f};
        f32x4 acc1 = {0.f, 0.f, 0.f, 0.f};
#pragma unroll
        for (int ks = 0; ks < 8; ++ks) {
            bf16x8 bfrag = *(const bf16x8*)(wp + ks * 32);
            acc0 = __builtin_amdgcn_mfma_f32_16x16x32_bf16(afrag[0][ks], bfrag, acc0, 0, 0, 0);
            acc1 = __builtin_amdgcn_mfma_f32_16x16x32_bf16(afrag[1][ks], bfrag, acc1, 0, 0, 0);
        }
        // C/D layout: col = lane&15, row = quad*4 + reg
        const float bias = b2[ncol];
#pragma unroll
        for (int r = 0; r < 4; ++r) {
            const int row0 = rowBase + quad * 4 + r;
            const int row1 = row0 + 16;
            out[row0 * 256 + ncol] = acc0[r] + bias;
            out[row1 * 256 + ncol] = acc1[r] + bias;
        }
    }
}

extern "C" void kernel_launch(void* const* d_in, const int* in_sizes, int n_in,
                              void* d_out, int out_size, void* d_ws, size_t ws_size,
                              hipStream_t stream) {
    const int*   TE = (const int*)  d_in[0];   // [B,S,2] integer (int32 or int64 words)
    const int*   Tp = (const int*)  d_in[1];   // scalar T
    const float* W1 = (const float*)d_in[2];   // [295,256]
    const float* b1 = (const float*)d_in[3];   // [256]
    const float* W2 = (const float*)d_in[4];   // [256,256]
    const float* b2 = (const float*)d_in[5];   // [256]
    __bf16* W2T  = (__bf16*)d_ws;              // 128 KB scratch
    int*    flag = (int*)((char*)d_ws + 131072);
    float*  out  = (float*)d_out;              // fp32 output (reference dtype)

    prep_w2t<<<256, 256, 0, stream>>>(W2, W2T, TE, flag);
    temb_gemm<<<M_TOTAL / BM, 256, 0, stream>>>(TE, Tp, W1, b1, W2T, b2, flag, out);
}

// Round 4
// 165.258 us; speedup vs baseline: 1.5074x; 1.5074x over previous
//
#include <hip/hip_runtime.h>
#include <hip/hip_bf16.h>

// Problem: B=64, S=2048, D=256, VOCAB=288. M = 131072.
//   day = TE[...,0] % 7 ; tod = TE[...,1] % T   (TE dtype runtime-probed 32/64)
//   h   = relu(W1[day] + W1[7+tod] + b1)   -> bf16, staged in LDS (coalesced)
//   out = h @ W2 + b2                      -> fp32, mfma_f32_16x16x32_bf16
// W2 pre-swizzled to fragment-linear bf16 (W2S) so B-frag loads are 1KB bursts.

typedef __bf16 bf16x4 __attribute__((ext_vector_type(4)));
typedef __bf16 bf16x8 __attribute__((ext_vector_type(8)));
typedef float  f32x4  __attribute__((ext_vector_type(4)));

#define M_TOTAL   131072
#define BM        128          // rows per block (4 waves x 32 rows)

// ws: [0,131072) = W2S bf16 fragment-linear; byte 131072: int flag (1 = TE int64)

// ---- prep: W2 [k][n] fp32 -> W2S fragment-linear bf16; + TE dtype probe ----
// W2S chunk id c = (nt*8 + ks)*64 + lane; chunk j -> W2[(ks*32+(lane>>4)*8+j)][nt*16+(lane&15)]
__global__ __launch_bounds__(256) void prep_w2s(const float* __restrict__ W2,
                                                __bf16* __restrict__ W2S,
                                                const int* __restrict__ TE32,
                                                int* __restrict__ flag) {
    int c = blockIdx.x * 256 + threadIdx.x;     // 8192 chunks
    if (c < 8192) {
        int lane = c & 63;
        int ksnt = c >> 6;
        int ks = ksnt & 7, nt = ksnt >> 3;
        int n  = nt * 16 + (lane & 15);
        int k0 = ks * 32 + (lane >> 4) * 8;
        bf16x8 w;
#pragma unroll
        for (int j = 0; j < 8; ++j) w[j] = (__bf16)W2[(k0 + j) * 256 + n];
        *(bf16x8*)(W2S + c * 8) = w;
    }
    // TE dtype probe: int64 => odd int32 words (high words of values<288) all 0
    if (blockIdx.x == 0 && threadIdx.x < 64) {
        int v = 0;
        for (int i = (int)threadIdx.x; i < 2048; i += 64) v |= TE32[2 * i + 1];
        unsigned long long nz = __ballot(v != 0);
        if (threadIdx.x == 0) *flag = (nz == 0ull) ? 1 : 0;
    }
}

// ---- main ------------------------------------------------------------------
__global__ __launch_bounds__(256, 2) void temb_gemm(
        const int*  __restrict__ TE32,  // [M,2] int32 or int64 word view
        const int*  __restrict__ Tp,    // scalar T (low word either way)
        const float* __restrict__ W1,   // [295,256]
        const float* __restrict__ b1,   // [256]
        const __bf16* __restrict__ W2S, // fragment-linear bf16 [8192*8]
        const float* __restrict__ b2,   // [256]
        const int*  __restrict__ flag,  // 1 if TE is int64
        float* __restrict__ out)        // [M,256] fp32
{
    __shared__ __bf16 h_lds[BM * 256];  // 64 KB exactly -> 2 blocks/CU

    const int T    = Tp[0];
    const int is64 = *flag;             // wave-uniform
    const int wave = threadIdx.x >> 6;
    const int lane = threadIdx.x & 63;
    const int m    = lane & 15;         // A row in tile / C col in tile
    const int quad = lane >> 4;         // k-chunk selector / C row-group
    const int rowBase = blockIdx.x * BM + wave * 32;   // this wave's 32 rows

    // b1 fragment for this lane's 4 columns (reused for all rows)
    const f32x4 b1v = *(const f32x4*)(b1 + lane * 4);

    // ---- phase 0: this wave's TE indices in lanes 0..31 ----
    int dayv = 0, todv = 0;
    if (lane < 32) {
        if (is64) {
            const int4 te = *(const int4*)(TE32 + 4 * (rowBase + lane));
            dayv = te.x; todv = te.z;
        } else {
            const int2 te = *(const int2*)(TE32 + 2 * (rowBase + lane));
            dayv = te.x; todv = te.y;
        }
        dayv %= 7; todv %= T;
    }

    // ---- phase 1: cooperative h build -> LDS (coalesced 1KB W1 row loads) ----
    const int hbase = wave * 32 * 256;
#pragma unroll 4
    for (int r = 0; r < 32; ++r) {
        const int day = __builtin_amdgcn_readfirstlane(__shfl(dayv, r));
        const int tod = __builtin_amdgcn_readfirstlane(__shfl(todv, r));
        const f32x4 a = *(const f32x4*)(W1 + day * 256 + lane * 4);
        const f32x4 b = *(const f32x4*)(W1 + (7 + tod) * 256 + lane * 4);
        bf16x4 hv;
#pragma unroll
        for (int j = 0; j < 4; ++j)
            hv[j] = (__bf16)fmaxf(a[j] + b[j] + b1v[j], 0.0f);
        *(bf16x4*)(h_lds + hbase + r * 256 + lane * 4) = hv;
    }
    __syncthreads();   // defensive (reads are wave-local, but cheap: once/block)

    // ---- phase 2: A-frags from LDS (held in registers for the whole N loop) ----
    // A layout: A[m = lane&15][k = quad*8 + j]
    bf16x8 afrag[2][8];
#pragma unroll
    for (int t = 0; t < 2; ++t)
#pragma unroll
        for (int ks = 0; ks < 8; ++ks)
            afrag[t][ks] = *(const bf16x8*)(h_lds + hbase + (t * 16 + m) * 256
                                            + ks * 32 + quad * 8);

    // per-lane bias values: b2[nt*16 + m]
    float b2r[16];
#pragma unroll
    for (int nt = 0; nt < 16; ++nt) b2r[nt] = b2[nt * 16 + m];

    // ---- phase 3: N loop; B-frag loads are contiguous 1KB bursts ----
    const __bf16* __restrict__ wp = W2S + lane * 8;
#pragma unroll 4
    for (int nt = 0; nt < 16; ++nt) {
        f32x4 acc0 = {0.f, 0.f, 0.f, 0.f};
        f32x4 acc1 = {0.f, 0.f, 0.f, 0.f};
#pragma unroll
        for (int ks = 0; ks < 8; ++ks) {
            bf16x8 bfrag = *(const bf16x8*)(wp + (nt * 8 + ks) * 512);
            acc0 = __builtin_amdgcn_mfma_f32_16x16x32_bf16(afrag[0][ks], bfrag, acc0, 0, 0, 0);
            acc1 = __builtin_amdgcn_mfma_f32_16x16x32_bf16(afrag[1][ks], bfrag, acc1, 0, 0, 0);
        }
        // C/D layout: col = lane&15, row = quad*4 + reg
        const int ncol = nt * 16 + m;
        const float bias = b2r[nt];
#pragma unroll
        for (int r = 0; r < 4; ++r) {
            const int row0 = rowBase + quad * 4 + r;
            out[row0 * 256 + ncol]        = acc0[r] + bias;
            out[(row0 + 16) * 256 + ncol] = acc1[r] + bias;
        }
    }
}

extern "C" void kernel_launch(void* const* d_in, const int* in_sizes, int n_in,
                              void* d_out, int out_size, void* d_ws, size_t ws_size,
                              hipStream_t stream) {
    const int*   TE = (const int*)  d_in[0];   // [B,S,2] integer words
    const int*   Tp = (const int*)  d_in[1];   // scalar T
    const float* W1 = (const float*)d_in[2];   // [295,256]
    const float* b1 = (const float*)d_in[3];   // [256]
    const float* W2 = (const float*)d_in[4];   // [256,256]
    const float* b2 = (const float*)d_in[5];   // [256]
    __bf16* W2S  = (__bf16*)d_ws;              // 128 KB fragment-linear W2
    int*    flag = (int*)((char*)d_ws + 131072);
    float*  out  = (float*)d_out;

    prep_w2s<<<32, 256, 0, stream>>>(W2, W2S, TE, flag);
    temb_gemm<<<M_TOTAL / BM, 256, 0, stream>>>(TE, Tp, W1, b1, W2S, b2, flag, out);
}